// Round 8
// baseline (132.568 us; speedup 1.0000x reference)
//
#include <hip/hip_runtime.h>
#include <math.h>

// Problem constants
#define NVAL  97336           // 46^3 valid window positions
#define NCH   8               // N*C = 2*4 channels

typedef unsigned short u16;
typedef __attribute__((ext_vector_type(8))) short bf16x8;
typedef __attribute__((ext_vector_type(4))) float f32x4;
typedef __attribute__((ext_vector_type(4))) unsigned int u32x4;

// LDS staging geometry (gram kernel)
#define LINE_B 336            // 3 copies * 112 B per (x,y,vol) z-line
#define COPY_B 112            // 48 bf16 (96 B) + 16 B pad (bank spread)
#define VOL_B  21504          // 64 lines * 336
#define SHIFT_LINE_U16 144    // global pre-shifted line: 3 copies * 48 u16

// ---------------------------------------------------------------------------
// Kernel 1: fused sigmoid/one-hot + 2x2x2 max-pool -> bf16, written as 3
// z-pre-shifted copies per line. Block 0 also zeroes the output scalar.
// ---------------------------------------------------------------------------
__global__ __launch_bounds__(256) void pool_kernel(
    const float* __restrict__ logits, const int* __restrict__ labels,
    u16* __restrict__ shifted, float* __restrict__ out) {
  int t = blockIdx.x * 256 + threadIdx.x;
  if (t == 0) out[0] = 0.0f;
  if (t >= 2 * 110592) return;
  int Z = t % 48; int tmp = t / 48;
  int Y = tmp % 48; tmp /= 48;
  int X = tmp % 48; int n = tmp / 48;
  int sb = (2 * X) * 9216 + (2 * Y) * 96 + 2 * Z;
  const int2* lb2 = (const int2*)(labels + n * 884736 + sb);
  int2 La = lb2[0], Lb = lb2[48], Lc = lb2[4608], Ld = lb2[4656];
  #pragma unroll
  for (int c = 0; c < 4; c++) {
    const float2* lg2 = (const float2*)(logits + (size_t)(n * 4 + c) * 884736 + sb);
    float2 v0 = lg2[0], v1 = lg2[48], v2 = lg2[4608], v3 = lg2[4656];
    float mx = fmaxf(fmaxf(fmaxf(v0.x, v0.y), fmaxf(v1.x, v1.y)),
                     fmaxf(fmaxf(v2.x, v2.y), fmaxf(v3.x, v3.y)));
    // max(sigmoid) == sigmoid(max); +1e-6 commutes with max
    float pr = 1.0f / (1.0f + expf(-mx)) + 1e-6f;
    int la = (La.x == c || La.y == c || Lb.x == c || Lb.y == c ||
              Lc.x == c || Lc.y == c || Ld.x == c || Ld.y == c);
    u16 la16 = la ? (u16)0x3F80 : (u16)0;         // bf16(1.0)
    unsigned int u = __float_as_uint(pr);          // round-to-nearest-even bf16
    u16 pr16 = (u16)((u + 0x7FFF + ((u >> 16) & 1)) >> 16);
    int ch = n * 4 + c;
    size_t lbase = ((size_t)(ch * 2 + 0) * 2304 + X * 48 + Y) * SHIFT_LINE_U16;
    size_t pbase = ((size_t)(ch * 2 + 1) * 2304 + X * 48 + Y) * SHIFT_LINE_U16;
    #pragma unroll
    for (int dz = 0; dz < 3; dz++) {
      int s = Z - dz;
      u16 lo = la16, po = pr16;
      if (s < 0) { s = 47 - (dz - 1 - Z); lo = 0; po = 0; }  // tail zero slots
      shifted[lbase + dz * 48 + s] = lo;
      shifted[pbase + dz * 48 + s] = po;
    }
  }
}

// ---------------------------------------------------------------------------
// Kernel 2: Gram via MFMA. W rows 0-26 = la shifts, 27-53 = pr shifts,
// 54 = ones (row sums for free), 55-63 = zero. G = (mask.W) W^T, upper
// triangle as 10 16x16 tiles. Block = (ch, 6x6 xy-tile of base positions).
// ---------------------------------------------------------------------------
#define MFMA16(A, B, C) __builtin_amdgcn_mfma_f32_16x16x32_bf16((A), (B), (C), 0, 0, 0)

#define STEP(BA, AM) do {                                                  \
    int _ba = (BA);                                                        \
    u32x4 ub0 = *(const u32x4*)(smem + _ba + laneC0);                      \
    u32x4 ub1 = *(const u32x4*)(smem + _ba + laneC1);                      \
    u32x4 ub2 = *(const u32x4*)(smem + _ba + laneC2);                      \
    u32x4 ub3 = *(const u32x4*)(smem + _ba + laneC3);                      \
    ub3 = iszero ? zer4 : (isones ? one4 : ub3);                           \
    u32x4 ua0 = ub0, ua1 = ub1, ua2 = ub2, ua3 = ub3;                      \
    ua0.w &= (AM); ua1.w &= (AM); ua2.w &= (AM); ua3.w &= (AM);            \
    bf16x8 A0 = __builtin_bit_cast(bf16x8, ua0);                           \
    bf16x8 A1 = __builtin_bit_cast(bf16x8, ua1);                           \
    bf16x8 A2 = __builtin_bit_cast(bf16x8, ua2);                           \
    bf16x8 A3 = __builtin_bit_cast(bf16x8, ua3);                           \
    bf16x8 B0 = __builtin_bit_cast(bf16x8, ub0);                           \
    bf16x8 B1 = __builtin_bit_cast(bf16x8, ub1);                           \
    bf16x8 B2 = __builtin_bit_cast(bf16x8, ub2);                           \
    bf16x8 B3 = __builtin_bit_cast(bf16x8, ub3);                           \
    acc0 = MFMA16(A0, B0, acc0);  acc1 = MFMA16(A0, B1, acc1);             \
    acc2 = MFMA16(A0, B2, acc2);  acc3 = MFMA16(A0, B3, acc3);             \
    acc4 = MFMA16(A1, B1, acc4);  acc5 = MFMA16(A1, B2, acc5);             \
    acc6 = MFMA16(A1, B3, acc6);  acc7 = MFMA16(A2, B2, acc7);             \
    acc8 = MFMA16(A2, B3, acc8);  acc9 = MFMA16(A3, B3, acc9);             \
  } while (0)

__global__ __launch_bounds__(256) void gram_kernel(
    const u16* __restrict__ shifted, float* __restrict__ partials) {
  __shared__ __align__(16) unsigned char smem[43008];
  int bx = blockIdx.x;
  int ch = bx >> 6, xt = (bx >> 3) & 7, yt = bx & 7;
  int X0 = xt * 6, Y0 = yt * 6;
  int tw = (xt == 7) ? 4 : 6, th = (yt == 7) ? 4 : 6;
  int tid = threadIdx.x;

  // Stage fixed 8x8 lines x 2 vols, 3 pre-shifted copies each, into LDS
  const u16* base = shifted + (size_t)ch * 2 * 2304 * SHIFT_LINE_U16;
  for (int j = tid; j < 2304; j += 256) {        // 2*64*18 chunks, 9 iters
    int chunk = j % 18; int li = j / 18;         // li 0..127
    int sy = li & 7, sx = (li >> 3) & 7, vol = li >> 6;
    int gx = X0 + sx; if (gx > 47) gx = 47;      // clamp: garbage, never read
    int gy = Y0 + sy; if (gy > 47) gy = 47;
    const u32x4* src = (const u32x4*)(base +
        ((size_t)vol * 2304 + gx * 48 + gy) * SHIFT_LINE_U16);
    u32x4 v = src[chunk];
    int dz = chunk / 6, cc = chunk - dz * 6;
    *(u32x4*)(smem + vol * VOL_B + ((sx << 3) + sy) * LINE_B + dz * COPY_B + cc * 16) = v;
  }
  __syncthreads();

  int lane = tid & 63, w = tid >> 6;
  int q = lane >> 4, rlo = lane & 15;
#define LANEC(F) ({ int _r = (F) * 16 + rlo; int _vol = 0, _s = 0;           \
    if (_r < 27) { _s = _r; } else if (_r < 54) { _vol = 1; _s = _r - 27; }  \
    int _dx = _s / 9, _dy = (_s / 3) % 3, _dz = _s % 3;                      \
    _vol * VOL_B + ((_dx << 3) + _dy) * LINE_B + _dz * COPY_B; })
  int laneC0 = LANEC(0), laneC1 = LANEC(1), laneC2 = LANEC(2), laneC3 = LANEC(3);
  unsigned int am1 = (q == 1) ? 0u : ~0u;
  unsigned int am2 = (q == 3) ? 0u : ~0u;
  bool isones = (rlo == 6);    // frag3 row 54 = ones
  bool iszero = (rlo > 6);     // frag3 rows 55-63 = zero
  u32x4 one4 = {0x3F803F80u, 0x3F803F80u, 0x3F803F80u, 0x3F803F80u};
  u32x4 zer4 = {0u, 0u, 0u, 0u};

  f32x4 acc0 = {0,0,0,0}, acc1 = {0,0,0,0}, acc2 = {0,0,0,0}, acc3 = {0,0,0,0};
  f32x4 acc4 = {0,0,0,0}, acc5 = {0,0,0,0}, acc6 = {0,0,0,0}, acc7 = {0,0,0,0};
  f32x4 acc8 = {0,0,0,0}, acc9 = {0,0,0,0};

  int npl = (tw * th) >> 1;
  for (int pl = w; pl < npl; pl += 4) {
    int L0 = 2 * pl, L1 = L0 + 1;
    int lx0 = L0 / th, ly0 = L0 - lx0 * th;
    int lx1 = L1 / th, ly1 = L1 - lx1 * th;
    int U0 = ((lx0 << 3) + ly0) * LINE_B;
    int U1 = ((lx1 << 3) + ly1) * LINE_B;
    STEP(U0 + 16 * q, ~0u);
    STEP((q < 2) ? (U0 + 64 + 16 * q) : (U1 + 16 * q - 32), am1);
    STEP(U1 + 32 + 16 * q, am2);
  }
  __syncthreads();

  float* Pf = (float*)smem;
#define FL(T, A) { float* _qp = Pf + w * 2560 + (T) * 256 + lane;            \
    _qp[0] = (A).x; _qp[64] = (A).y; _qp[128] = (A).z; _qp[192] = (A).w; }
  FL(0, acc0) FL(1, acc1) FL(2, acc2) FL(3, acc3) FL(4, acc4)
  FL(5, acc5) FL(6, acc6) FL(7, acc7) FL(8, acc8) FL(9, acc9)
  __syncthreads();
  float* dst = partials + (size_t)(ch * 64 + xt * 8 + yt) * 2560;
  for (int u2 = tid; u2 < 2560; u2 += 256)
    dst[u2] = Pf[u2] + Pf[u2 + 2560] + Pf[u2 + 5120] + Pf[u2 + 7680];
}

// ---------------------------------------------------------------------------
// Kernel 3: per-channel partial reduction (fp64, into LDS) + bordered 54x54
// rank-8 blocked elimination (6 phases + 6x6 tail). One block per channel.
// M = [[pr_cov+aI, B^T],[B, la_cov+aI]]; pivots 27..53 = chol(appro+aI)^2.
// MS even -> 8-double borders are 16-B aligned (ds_read_b128).
// ---------------------------------------------------------------------------
#define MS 56   // row stride (doubles), even for 16-B alignment
__device__ inline double g54(const double* __restrict__ G, int R, int C) {
  int I = R >> 4, J = C >> 4;
  if (I > J) { int tt = R; R = C; C = tt; I = R >> 4; J = C >> 4; }
  int tile = 4 * I - ((I * (I - 1)) >> 1) + (J - I);
  int r = R & 15, c = C & 15;
  return G[tile * 256 + (r & 3) * 64 + ((r >> 2) << 4) + c];
}

__device__ inline int tri_row(int u) {
  int a = (int)((sqrtf(8.0f * (float)u + 1.0f) - 1.0f) * 0.5f);
  while ((a + 1) * (a + 2) / 2 <= u) a++;
  while (a * (a + 1) / 2 > u) a--;
  return a;
}

__global__ __launch_bounds__(256) void stage2_kernel(
    const float* __restrict__ partials, float* __restrict__ out) {
  __shared__ double gsum[2560];
  __shared__ double M[54 * MS];
  __shared__ double slv[27], spv[27], piv[54], lred[27];
  int ch = blockIdx.x, tid = threadIdx.x;
  const double Minv = 1.0 / (double)NVAL;
  const double alpha = 5e-4;

  // Reduce this channel's 64 tile-partials (fp64) into LDS
  const float* p0 = partials + (size_t)ch * 64 * 2560;
  for (int so = tid; so < 2560; so += 256) {
    const float* p = p0 + so;
    double s = 0.0;
    #pragma unroll 8
    for (int t = 0; t < 64; t++) s += (double)p[t * 2560];
    gsum[so] = s;
  }
  __syncthreads();
  const double* G = gsum;

  if (tid < 27) { slv[tid] = g54(G, tid, 54); spv[tid] = g54(G, 27 + tid, 54); }
  __syncthreads();
  // Build lower triangle of bordered matrix: 0..26 = pr dims, 27..53 = la
  for (int u = tid; u < 1485; u += 256) {
    int a = tri_row(u);
    int b = u - a * (a + 1) / 2;               // b <= a
    double v;
    if (a < 27) {                               // pr-pr
      v = g54(G, 27 + a, 27 + b) - spv[a] * spv[b] * Minv + ((a == b) ? alpha : 0.0);
    } else if (b >= 27) {                       // la-la
      int d = a - 27, e = b - 27;
      v = g54(G, d, e) - slv[d] * slv[e] * Minv + ((d == e) ? alpha : 0.0);
    } else {                                    // la row, pr col
      v = g54(G, a - 27, 27 + b) - slv[a - 27] * spv[b] * Minv;
    }
    M[a * MS + b] = v;
  }
  __syncthreads();

  #pragma unroll 1
  for (int phase = 0; phase < 6; phase++) {
    int k0 = phase * 8;
    // Load lower 8x8 pivot block (broadcast reads), factor LDL^T in regs
    double P[8][8];
    #pragma unroll
    for (int k = 0; k < 8; k++)
      #pragma unroll
      for (int j = 0; j <= k; j++)
        P[k][j] = M[(k0 + k) * MS + (k0 + j)];
    double idv[8];
    #pragma unroll
    for (int k = 0; k < 8; k++) {
      idv[k] = 1.0 / P[k][k];
      #pragma unroll
      for (int i = k + 1; i < 8; i++) {
        double l = P[i][k] * idv[k];
        #pragma unroll
        for (int j = k + 1; j <= i; j++)
          P[i][j] -= l * P[j][k];
      }
      #pragma unroll
      for (int i = k + 1; i < 8; i++) P[i][k] *= idv[k];
    }
    if (tid == 0) {
      #pragma unroll
      for (int k = 0; k < 8; k++) piv[k0 + k] = P[k][k];
    }
    int base = k0 + 8, n = 54 - base;
    int ncell = n * (n + 1) / 2;
    for (int u = tid; u < ncell; u += 256) {
      int ii = tri_row(u);
      int jj = u - ii * (ii + 1) / 2;
      int i = base + ii, j = base + jj;
      // 16-B aligned vector loads of the 8-double borders
      const double2* Ai = (const double2*)(M + i * MS + k0);
      const double2* Bj = (const double2*)(M + j * MS + k0);
      double2 a01 = Ai[0], a23 = Ai[1], a45 = Ai[2], a67 = Ai[3];
      double2 b01 = Bj[0], b23 = Bj[1], b45 = Bj[2], b67 = Bj[3];
      double av[8] = {a01.x, a01.y, a23.x, a23.y, a45.x, a45.y, a67.x, a67.y};
      double bv[8] = {b01.x, b01.y, b23.x, b23.y, b45.x, b45.y, b67.x, b67.y};
      #pragma unroll
      for (int k = 1; k < 8; k++) {
        #pragma unroll
        for (int m = 0; m < k; m++) {
          av[k] -= P[k][m] * av[m];
          bv[k] -= P[k][m] * bv[m];
        }
      }
      double acc = 0.0;
      #pragma unroll
      for (int k = 0; k < 8; k++) acc += av[k] * (bv[k] * idv[k]);
      M[i * MS + j] -= acc;
    }
    __syncthreads();
  }

  // Tail: 6x6 trailing block, pivots 48..53
  if (tid == 0) {
    double T[6][6];
    #pragma unroll
    for (int k = 0; k < 6; k++)
      #pragma unroll
      for (int j = 0; j <= k; j++)
        T[k][j] = M[(48 + k) * MS + (48 + j)];
    #pragma unroll
    for (int k = 0; k < 6; k++) {
      double dk = T[k][k];
      piv[48 + k] = dk;
      double id = 1.0 / dk;
      #pragma unroll
      for (int i = k + 1; i < 6; i++) {
        double l = T[i][k] * id;
        #pragma unroll
        for (int j = k + 1; j <= i; j++)
          T[i][j] -= l * T[j][k];
      }
    }
  }
  __syncthreads();

  if (tid < 27) lred[tid] = log(sqrt(piv[27 + tid]) + 1e-8);
  __syncthreads();
  if (tid == 0) {
    double s = 0.0;
    for (int i = 0; i < 27; i++) s += lred[i];
    atomicAdd(out, (float)(s / 54.0));
  }
}

// ---------------------------------------------------------------------------
extern "C" void kernel_launch(void* const* d_in, const int* in_sizes, int n_in,
                              void* d_out, int out_size, void* d_ws, size_t ws_size,
                              hipStream_t stream) {
  const float* logits = (const float*)d_in[0];
  const int* labels = (const int*)d_in[1];
  float* out = (float*)d_out;

  // ws layout: partials fp32 (5 MB) | shifted bf16 (10.6 MB)
  float* partials = (float*)d_ws;
  u16* shifted = (u16*)((char*)d_ws + 5242880);

  pool_kernel<<<864, 256, 0, stream>>>(logits, labels, shifted, out);
  gram_kernel<<<512, 256, 0, stream>>>(shifted, partials);
  stage2_kernel<<<NCH, 256, 0, stream>>>(partials, out);
}

// Round 9
// 106.116 us; speedup vs baseline: 1.2493x; 1.2493x over previous
//
#include <hip/hip_runtime.h>
#include <math.h>

// Problem constants
#define NVAL  97336           // 46^3 valid window positions
#define NCH   8               // N*C = 2*4 channels

typedef unsigned short u16;
typedef __attribute__((ext_vector_type(8))) short bf16x8;
typedef __attribute__((ext_vector_type(4))) float f32x4;
typedef __attribute__((ext_vector_type(4))) unsigned int u32x4;

// LDS staging geometry (gram kernel)
#define LINE_B 336            // 3 copies * 112 B per (x,y,vol) z-line
#define COPY_B 112            // 48 bf16 (96 B) + 16 B pad (bank spread)
#define VOL_B  21504          // 64 lines * 336
#define SHIFT_LINE_U16 144    // global pre-shifted line: 3 copies * 48 u16

// ---------------------------------------------------------------------------
// Kernel 1: fused sigmoid/one-hot + 2x2x2 max-pool -> bf16, written as 3
// z-pre-shifted copies per line. Also zeroes out[] (block0) and the fp32
// Gram accumulators (blocks 0..79) -- ordering via kernel boundary.
// ---------------------------------------------------------------------------
__global__ __launch_bounds__(256) void pool_kernel(
    const float* __restrict__ logits, const int* __restrict__ labels,
    u16* __restrict__ shifted, float* __restrict__ gacc,
    float* __restrict__ out) {
  int t = blockIdx.x * 256 + threadIdx.x;
  if (t == 0) out[0] = 0.0f;
  if (blockIdx.x < 80) gacc[blockIdx.x * 256 + threadIdx.x] = 0.0f;
  if (t >= 2 * 110592) return;
  int Z = t % 48; int tmp = t / 48;
  int Y = tmp % 48; tmp /= 48;
  int X = tmp % 48; int n = tmp / 48;
  int sb = (2 * X) * 9216 + (2 * Y) * 96 + 2 * Z;
  const int2* lb2 = (const int2*)(labels + n * 884736 + sb);
  int2 La = lb2[0], Lb = lb2[48], Lc = lb2[4608], Ld = lb2[4656];
  #pragma unroll
  for (int c = 0; c < 4; c++) {
    const float2* lg2 = (const float2*)(logits + (size_t)(n * 4 + c) * 884736 + sb);
    float2 v0 = lg2[0], v1 = lg2[48], v2 = lg2[4608], v3 = lg2[4656];
    float mx = fmaxf(fmaxf(fmaxf(v0.x, v0.y), fmaxf(v1.x, v1.y)),
                     fmaxf(fmaxf(v2.x, v2.y), fmaxf(v3.x, v3.y)));
    // max(sigmoid) == sigmoid(max); +1e-6 commutes with max
    float pr = 1.0f / (1.0f + expf(-mx)) + 1e-6f;
    int la = (La.x == c || La.y == c || Lb.x == c || Lb.y == c ||
              Lc.x == c || Lc.y == c || Ld.x == c || Ld.y == c);
    u16 la16 = la ? (u16)0x3F80 : (u16)0;         // bf16(1.0)
    unsigned int u = __float_as_uint(pr);          // round-to-nearest-even bf16
    u16 pr16 = (u16)((u + 0x7FFF + ((u >> 16) & 1)) >> 16);
    int ch = n * 4 + c;
    size_t lbase = ((size_t)(ch * 2 + 0) * 2304 + X * 48 + Y) * SHIFT_LINE_U16;
    size_t pbase = ((size_t)(ch * 2 + 1) * 2304 + X * 48 + Y) * SHIFT_LINE_U16;
    #pragma unroll
    for (int dz = 0; dz < 3; dz++) {
      int s = Z - dz;
      u16 lo = la16, po = pr16;
      if (s < 0) { s = 47 - (dz - 1 - Z); lo = 0; po = 0; }  // tail zero slots
      shifted[lbase + dz * 48 + s] = lo;
      shifted[pbase + dz * 48 + s] = po;
    }
  }
}

// ---------------------------------------------------------------------------
// Kernel 2: Gram via MFMA. W rows 0-26 = la shifts, 27-53 = pr shifts,
// 54 = ones (row sums for free), 55-63 = zero. G = (mask.W) W^T, upper
// triangle as 10 16x16 tiles. Block = (ch, 6x6 xy-tile); partials are
// fp32-atomicAdd'ed into the per-channel global Gram accumulator.
// ---------------------------------------------------------------------------
#define MFMA16(A, B, C) __builtin_amdgcn_mfma_f32_16x16x32_bf16((A), (B), (C), 0, 0, 0)

#define STEP(BA, AM) do {                                                  \
    int _ba = (BA);                                                        \
    u32x4 ub0 = *(const u32x4*)(smem + _ba + laneC0);                      \
    u32x4 ub1 = *(const u32x4*)(smem + _ba + laneC1);                      \
    u32x4 ub2 = *(const u32x4*)(smem + _ba + laneC2);                      \
    u32x4 ub3 = *(const u32x4*)(smem + _ba + laneC3);                      \
    ub3 = iszero ? zer4 : (isones ? one4 : ub3);                           \
    u32x4 ua0 = ub0, ua1 = ub1, ua2 = ub2, ua3 = ub3;                      \
    ua0.w &= (AM); ua1.w &= (AM); ua2.w &= (AM); ua3.w &= (AM);            \
    bf16x8 A0 = __builtin_bit_cast(bf16x8, ua0);                           \
    bf16x8 A1 = __builtin_bit_cast(bf16x8, ua1);                           \
    bf16x8 A2 = __builtin_bit_cast(bf16x8, ua2);                           \
    bf16x8 A3 = __builtin_bit_cast(bf16x8, ua3);                           \
    bf16x8 B0 = __builtin_bit_cast(bf16x8, ub0);                           \
    bf16x8 B1 = __builtin_bit_cast(bf16x8, ub1);                           \
    bf16x8 B2 = __builtin_bit_cast(bf16x8, ub2);                           \
    bf16x8 B3 = __builtin_bit_cast(bf16x8, ub3);                           \
    acc0 = MFMA16(A0, B0, acc0);  acc1 = MFMA16(A0, B1, acc1);             \
    acc2 = MFMA16(A0, B2, acc2);  acc3 = MFMA16(A0, B3, acc3);             \
    acc4 = MFMA16(A1, B1, acc4);  acc5 = MFMA16(A1, B2, acc5);             \
    acc6 = MFMA16(A1, B3, acc6);  acc7 = MFMA16(A2, B2, acc7);             \
    acc8 = MFMA16(A2, B3, acc8);  acc9 = MFMA16(A3, B3, acc9);             \
  } while (0)

__global__ __launch_bounds__(256) void gram_kernel(
    const u16* __restrict__ shifted, float* __restrict__ gacc) {
  __shared__ __align__(16) unsigned char smem[43008];
  int bx = blockIdx.x;
  int ch = bx >> 6, xt = (bx >> 3) & 7, yt = bx & 7;
  int X0 = xt * 6, Y0 = yt * 6;
  int tw = (xt == 7) ? 4 : 6, th = (yt == 7) ? 4 : 6;
  int tid = threadIdx.x;

  // Stage fixed 8x8 lines x 2 vols, 3 pre-shifted copies each, into LDS
  const u16* base = shifted + (size_t)ch * 2 * 2304 * SHIFT_LINE_U16;
  for (int j = tid; j < 2304; j += 256) {        // 2*64*18 chunks, 9 iters
    int chunk = j % 18; int li = j / 18;         // li 0..127
    int sy = li & 7, sx = (li >> 3) & 7, vol = li >> 6;
    int gx = X0 + sx; if (gx > 47) gx = 47;      // clamp: garbage, never read
    int gy = Y0 + sy; if (gy > 47) gy = 47;
    const u32x4* src = (const u32x4*)(base +
        ((size_t)vol * 2304 + gx * 48 + gy) * SHIFT_LINE_U16);
    u32x4 v = src[chunk];
    int dz = chunk / 6, cc = chunk - dz * 6;
    *(u32x4*)(smem + vol * VOL_B + ((sx << 3) + sy) * LINE_B + dz * COPY_B + cc * 16) = v;
  }
  __syncthreads();

  int lane = tid & 63, w = tid >> 6;
  int q = lane >> 4, rlo = lane & 15;
#define LANEC(F) ({ int _r = (F) * 16 + rlo; int _vol = 0, _s = 0;           \
    if (_r < 27) { _s = _r; } else if (_r < 54) { _vol = 1; _s = _r - 27; }  \
    int _dx = _s / 9, _dy = (_s / 3) % 3, _dz = _s % 3;                      \
    _vol * VOL_B + ((_dx << 3) + _dy) * LINE_B + _dz * COPY_B; })
  int laneC0 = LANEC(0), laneC1 = LANEC(1), laneC2 = LANEC(2), laneC3 = LANEC(3);
  unsigned int am1 = (q == 1) ? 0u : ~0u;
  unsigned int am2 = (q == 3) ? 0u : ~0u;
  bool isones = (rlo == 6);    // frag3 row 54 = ones
  bool iszero = (rlo > 6);     // frag3 rows 55-63 = zero
  u32x4 one4 = {0x3F803F80u, 0x3F803F80u, 0x3F803F80u, 0x3F803F80u};
  u32x4 zer4 = {0u, 0u, 0u, 0u};

  f32x4 acc0 = {0,0,0,0}, acc1 = {0,0,0,0}, acc2 = {0,0,0,0}, acc3 = {0,0,0,0};
  f32x4 acc4 = {0,0,0,0}, acc5 = {0,0,0,0}, acc6 = {0,0,0,0}, acc7 = {0,0,0,0};
  f32x4 acc8 = {0,0,0,0}, acc9 = {0,0,0,0};

  int npl = (tw * th) >> 1;
  for (int pl = w; pl < npl; pl += 4) {
    int L0 = 2 * pl, L1 = L0 + 1;
    int lx0 = L0 / th, ly0 = L0 - lx0 * th;
    int lx1 = L1 / th, ly1 = L1 - lx1 * th;
    int U0 = ((lx0 << 3) + ly0) * LINE_B;
    int U1 = ((lx1 << 3) + ly1) * LINE_B;
    STEP(U0 + 16 * q, ~0u);
    STEP((q < 2) ? (U0 + 64 + 16 * q) : (U1 + 16 * q - 32), am1);
    STEP(U1 + 32 + 16 * q, am2);
  }
  __syncthreads();

  float* Pf = (float*)smem;
#define FL(T, A) { float* _qp = Pf + w * 2560 + (T) * 256 + lane;            \
    _qp[0] = (A).x; _qp[64] = (A).y; _qp[128] = (A).z; _qp[192] = (A).w; }
  FL(0, acc0) FL(1, acc1) FL(2, acc2) FL(3, acc3) FL(4, acc4)
  FL(5, acc5) FL(6, acc6) FL(7, acc7) FL(8, acc8) FL(9, acc9)
  __syncthreads();
  float* dst = gacc + (size_t)ch * 2560;
  for (int u2 = tid; u2 < 2560; u2 += 256)
    atomicAdd(&dst[u2], Pf[u2] + Pf[u2 + 2560] + Pf[u2 + 5120] + Pf[u2 + 7680]);
}

// ---------------------------------------------------------------------------
// Kernel 3: bordered 54x54 rank-8 blocked elimination (6 phases + 6x6 tail).
// One block per channel, reading the fp32 global Gram (10 KB).
// M = [[pr_cov+aI, B^T],[B, la_cov+aI]]; pivots 27..53 = chol(appro+aI)^2.
// MS even -> 8-double borders are 16-B aligned (ds_read_b128).
// ---------------------------------------------------------------------------
#define MS 56   // row stride (doubles), even for 16-B alignment
__device__ inline double g54(const float* __restrict__ G, int R, int C) {
  int I = R >> 4, J = C >> 4;
  if (I > J) { int tt = R; R = C; C = tt; I = R >> 4; J = C >> 4; }
  int tile = 4 * I - ((I * (I - 1)) >> 1) + (J - I);
  int r = R & 15, c = C & 15;
  return (double)G[tile * 256 + (r & 3) * 64 + ((r >> 2) << 4) + c];
}

__device__ inline int tri_row(int u) {
  int a = (int)((sqrtf(8.0f * (float)u + 1.0f) - 1.0f) * 0.5f);
  while ((a + 1) * (a + 2) / 2 <= u) a++;
  while (a * (a + 1) / 2 > u) a--;
  return a;
}

__global__ __launch_bounds__(256) void stage2_kernel(
    const float* __restrict__ gacc, float* __restrict__ out) {
  __shared__ double M[54 * MS];
  __shared__ double slv[27], spv[27], piv[54], lred[27];
  int ch = blockIdx.x, tid = threadIdx.x;
  const double Minv = 1.0 / (double)NVAL;
  const double alpha = 5e-4;
  const float* G = gacc + (size_t)ch * 2560;

  if (tid < 27) { slv[tid] = g54(G, tid, 54); spv[tid] = g54(G, 27 + tid, 54); }
  __syncthreads();
  // Build lower triangle of bordered matrix: 0..26 = pr dims, 27..53 = la
  for (int u = tid; u < 1485; u += 256) {
    int a = tri_row(u);
    int b = u - a * (a + 1) / 2;               // b <= a
    double v;
    if (a < 27) {                               // pr-pr
      v = g54(G, 27 + a, 27 + b) - spv[a] * spv[b] * Minv + ((a == b) ? alpha : 0.0);
    } else if (b >= 27) {                       // la-la
      int d = a - 27, e = b - 27;
      v = g54(G, d, e) - slv[d] * slv[e] * Minv + ((d == e) ? alpha : 0.0);
    } else {                                    // la row, pr col
      v = g54(G, a - 27, 27 + b) - slv[a - 27] * spv[b] * Minv;
    }
    M[a * MS + b] = v;
  }
  __syncthreads();

  #pragma unroll 1
  for (int phase = 0; phase < 6; phase++) {
    int k0 = phase * 8;
    // Load lower 8x8 pivot block (broadcast reads), factor LDL^T in regs
    double P[8][8];
    #pragma unroll
    for (int k = 0; k < 8; k++)
      #pragma unroll
      for (int j = 0; j <= k; j++)
        P[k][j] = M[(k0 + k) * MS + (k0 + j)];
    double idv[8];
    #pragma unroll
    for (int k = 0; k < 8; k++) {
      idv[k] = 1.0 / P[k][k];
      #pragma unroll
      for (int i = k + 1; i < 8; i++) {
        double l = P[i][k] * idv[k];
        #pragma unroll
        for (int j = k + 1; j <= i; j++)
          P[i][j] -= l * P[j][k];
      }
      #pragma unroll
      for (int i = k + 1; i < 8; i++) P[i][k] *= idv[k];
    }
    if (tid == 0) {
      #pragma unroll
      for (int k = 0; k < 8; k++) piv[k0 + k] = P[k][k];
    }
    int base = k0 + 8, n = 54 - base;
    int ncell = n * (n + 1) / 2;
    for (int u = tid; u < ncell; u += 256) {
      int ii = tri_row(u);
      int jj = u - ii * (ii + 1) / 2;
      int i = base + ii, j = base + jj;
      // 16-B aligned vector loads of the 8-double borders
      const double2* Ai = (const double2*)(M + i * MS + k0);
      const double2* Bj = (const double2*)(M + j * MS + k0);
      double2 a01 = Ai[0], a23 = Ai[1], a45 = Ai[2], a67 = Ai[3];
      double2 b01 = Bj[0], b23 = Bj[1], b45 = Bj[2], b67 = Bj[3];
      double av[8] = {a01.x, a01.y, a23.x, a23.y, a45.x, a45.y, a67.x, a67.y};
      double bv[8] = {b01.x, b01.y, b23.x, b23.y, b45.x, b45.y, b67.x, b67.y};
      #pragma unroll
      for (int k = 1; k < 8; k++) {
        #pragma unroll
        for (int m = 0; m < k; m++) {
          av[k] -= P[k][m] * av[m];
          bv[k] -= P[k][m] * bv[m];
        }
      }
      double acc = 0.0;
      #pragma unroll
      for (int k = 0; k < 8; k++) acc += av[k] * (bv[k] * idv[k]);
      M[i * MS + j] -= acc;
    }
    __syncthreads();
  }

  // Tail: 6x6 trailing block, pivots 48..53
  if (tid == 0) {
    double T[6][6];
    #pragma unroll
    for (int k = 0; k < 6; k++)
      #pragma unroll
      for (int j = 0; j <= k; j++)
        T[k][j] = M[(48 + k) * MS + (48 + j)];
    #pragma unroll
    for (int k = 0; k < 6; k++) {
      double dk = T[k][k];
      piv[48 + k] = dk;
      double id = 1.0 / dk;
      #pragma unroll
      for (int i = k + 1; i < 6; i++) {
        double l = T[i][k] * id;
        #pragma unroll
        for (int j = k + 1; j <= i; j++)
          T[i][j] -= l * T[j][k];
      }
    }
  }
  __syncthreads();

  if (tid < 27) lred[tid] = log(sqrt(piv[27 + tid]) + 1e-8);
  __syncthreads();
  if (tid == 0) {
    double s = 0.0;
    for (int i = 0; i < 27; i++) s += lred[i];
    atomicAdd(out, (float)(s / 54.0));
  }
}

// ---------------------------------------------------------------------------
extern "C" void kernel_launch(void* const* d_in, const int* in_sizes, int n_in,
                              void* d_out, int out_size, void* d_ws, size_t ws_size,
                              hipStream_t stream) {
  const float* logits = (const float*)d_in[0];
  const int* labels = (const int*)d_in[1];
  float* out = (float*)d_out;

  // ws layout: gacc fp32 (80 KB, zeroed by pool) | shifted bf16 (10.6 MB)
  float* gacc = (float*)d_ws;
  u16* shifted = (u16*)((char*)d_ws + 131072);

  pool_kernel<<<864, 256, 0, stream>>>(logits, labels, shifted, gacc, out);
  gram_kernel<<<512, 256, 0, stream>>>(shifted, gacc);
  stage2_kernel<<<NCH, 256, 0, stream>>>(gacc, out);
}

// Round 10
// 102.901 us; speedup vs baseline: 1.2883x; 1.0312x over previous
//
#include <hip/hip_runtime.h>
#include <math.h>

// Problem constants
#define NVAL  97336           // 46^3 valid window positions
#define NCH   8               // N*C = 2*4 channels

typedef unsigned short u16;
typedef unsigned int u32;
typedef __attribute__((ext_vector_type(8))) short bf16x8;
typedef __attribute__((ext_vector_type(4))) float f32x4;
typedef __attribute__((ext_vector_type(4))) unsigned int u32x4;

// LDS staging geometry (gram kernel)
#define LINE_B 336            // 3 copies * 112 B per (x,y,vol) z-line
#define COPY_B 112            // 48 bf16 (96 B) + 16 B pad (bank spread)
#define VOL_B  21504          // 64 lines * 336
#define GLINE_U16 48          // global line: single copy, 48 u16 (96 B)

// ---------------------------------------------------------------------------
// Kernel 1: fused sigmoid/one-hot + 2x2x2 max-pool -> bf16, single copy per
// z-line. Also zeroes out[] (block0) and the fp32 Gram accumulators
// (blocks 0..79) -- ordering via kernel boundary (same-stream serialization).
// ---------------------------------------------------------------------------
__global__ __launch_bounds__(256) void pool_kernel(
    const float* __restrict__ logits, const int* __restrict__ labels,
    u16* __restrict__ shifted, float* __restrict__ gacc,
    float* __restrict__ out) {
  int t = blockIdx.x * 256 + threadIdx.x;
  if (t == 0) out[0] = 0.0f;
  if (blockIdx.x < 80) gacc[blockIdx.x * 256 + threadIdx.x] = 0.0f;
  if (t >= 2 * 110592) return;
  int Z = t % 48; int tmp = t / 48;
  int Y = tmp % 48; tmp /= 48;
  int X = tmp % 48; int n = tmp / 48;
  int sb = (2 * X) * 9216 + (2 * Y) * 96 + 2 * Z;
  const int2* lb2 = (const int2*)(labels + n * 884736 + sb);
  int2 La = lb2[0], Lb = lb2[48], Lc = lb2[4608], Ld = lb2[4656];
  #pragma unroll
  for (int c = 0; c < 4; c++) {
    const float2* lg2 = (const float2*)(logits + (size_t)(n * 4 + c) * 884736 + sb);
    float2 v0 = lg2[0], v1 = lg2[48], v2 = lg2[4608], v3 = lg2[4656];
    float mx = fmaxf(fmaxf(fmaxf(v0.x, v0.y), fmaxf(v1.x, v1.y)),
                     fmaxf(fmaxf(v2.x, v2.y), fmaxf(v3.x, v3.y)));
    // max(sigmoid) == sigmoid(max); +1e-6 commutes with max
    float pr = 1.0f / (1.0f + expf(-mx)) + 1e-6f;
    int la = (La.x == c || La.y == c || Lb.x == c || Lb.y == c ||
              Lc.x == c || Lc.y == c || Ld.x == c || Ld.y == c);
    u16 la16 = la ? (u16)0x3F80 : (u16)0;         // bf16(1.0)
    unsigned int u = __float_as_uint(pr);          // round-to-nearest-even bf16
    u16 pr16 = (u16)((u + 0x7FFF + ((u >> 16) & 1)) >> 16);
    int ch = n * 4 + c;
    shifted[((size_t)(ch * 2 + 0) * 2304 + X * 48 + Y) * GLINE_U16 + Z] = la16;
    shifted[((size_t)(ch * 2 + 1) * 2304 + X * 48 + Y) * GLINE_U16 + Z] = pr16;
  }
}

// ---------------------------------------------------------------------------
// Kernel 2: Gram via MFMA. W rows 0-26 = la shifts, 27-53 = pr shifts,
// 54 = ones (row sums for free), 55-63 = zero. G = (mask.W) W^T, upper
// triangle as 10 16x16 tiles. Block = (ch, 6x6 xy-tile). The 3 z-shifted
// copies are built IN-REGISTER during staging (funnel shifts); tail chunks
// get 0 so slots z>=46+dz stay zero exactly as the pre-shifted layout did.
// Partials are fp32-atomicAdd'ed into the per-channel global Gram.
// ---------------------------------------------------------------------------
#define MFMA16(A, B, C) __builtin_amdgcn_mfma_f32_16x16x32_bf16((A), (B), (C), 0, 0, 0)

#define STEP(BA, AM) do {                                                  \
    int _ba = (BA);                                                        \
    u32x4 ub0 = *(const u32x4*)(smem + _ba + laneC0);                      \
    u32x4 ub1 = *(const u32x4*)(smem + _ba + laneC1);                      \
    u32x4 ub2 = *(const u32x4*)(smem + _ba + laneC2);                      \
    u32x4 ub3 = *(const u32x4*)(smem + _ba + laneC3);                      \
    ub3 = iszero ? zer4 : (isones ? one4 : ub3);                           \
    u32x4 ua0 = ub0, ua1 = ub1, ua2 = ub2, ua3 = ub3;                      \
    ua0.w &= (AM); ua1.w &= (AM); ua2.w &= (AM); ua3.w &= (AM);            \
    bf16x8 A0 = __builtin_bit_cast(bf16x8, ua0);                           \
    bf16x8 A1 = __builtin_bit_cast(bf16x8, ua1);                           \
    bf16x8 A2 = __builtin_bit_cast(bf16x8, ua2);                           \
    bf16x8 A3 = __builtin_bit_cast(bf16x8, ua3);                           \
    bf16x8 B0 = __builtin_bit_cast(bf16x8, ub0);                           \
    bf16x8 B1 = __builtin_bit_cast(bf16x8, ub1);                           \
    bf16x8 B2 = __builtin_bit_cast(bf16x8, ub2);                           \
    bf16x8 B3 = __builtin_bit_cast(bf16x8, ub3);                           \
    acc0 = MFMA16(A0, B0, acc0);  acc1 = MFMA16(A0, B1, acc1);             \
    acc2 = MFMA16(A0, B2, acc2);  acc3 = MFMA16(A0, B3, acc3);             \
    acc4 = MFMA16(A1, B1, acc4);  acc5 = MFMA16(A1, B2, acc5);             \
    acc6 = MFMA16(A1, B3, acc6);  acc7 = MFMA16(A2, B2, acc7);             \
    acc8 = MFMA16(A2, B3, acc8);  acc9 = MFMA16(A3, B3, acc9);             \
  } while (0)

__global__ __launch_bounds__(256) void gram_kernel(
    const u16* __restrict__ shifted, float* __restrict__ gacc) {
  __shared__ __align__(16) unsigned char smem[43008];
  int bx = blockIdx.x;
  int ch = bx >> 6, xt = (bx >> 3) & 7, yt = bx & 7;
  int X0 = xt * 6, Y0 = yt * 6;
  int tw = (xt == 7) ? 4 : 6, th = (yt == 7) ? 4 : 6;
  int tid = threadIdx.x;

  // Stage fixed 8x8 lines x 2 vols; build 3 shifted copies in-register.
  const u16* base = shifted + (size_t)ch * 2 * 2304 * GLINE_U16;
  for (int j = tid; j < 768; j += 256) {         // 128 lines * 6 chunks
    int chunk = j % 6; int li = j / 6;           // li 0..127
    int sy = li & 7, sx = (li >> 3) & 7, vol = li >> 6;
    int gx = X0 + sx; if (gx > 47) gx = 47;      // clamp: garbage, never read
    int gy = Y0 + sy; if (gy > 47) gy = 47;
    const u32* src = (const u32*)(base +
        ((size_t)vol * 2304 + gx * 48 + gy) * GLINE_U16);
    u32x4 v = *(const u32x4*)(src + chunk * 4);
    u32 d4 = (chunk < 5) ? src[chunk * 4 + 4] : 0u;   // next dword; 0 at tail
    unsigned char* dst = smem + vol * VOL_B + ((sx << 3) + sy) * LINE_B + chunk * 16;
    *(u32x4*)(dst) = v;                                        // copy dz=0
    u32x4 s1 = { (v.x >> 16) | (v.y << 16), (v.y >> 16) | (v.z << 16),
                 (v.z >> 16) | (v.w << 16), (v.w >> 16) | (d4 << 16) };
    *(u32x4*)(dst + COPY_B) = s1;                              // copy dz=1
    u32x4 s2 = { v.y, v.z, v.w, d4 };
    *(u32x4*)(dst + 2 * COPY_B) = s2;                          // copy dz=2
  }
  __syncthreads();

  int lane = tid & 63, w = tid >> 6;
  int q = lane >> 4, rlo = lane & 15;
#define LANEC(F) ({ int _r = (F) * 16 + rlo; int _vol = 0, _s = 0;           \
    if (_r < 27) { _s = _r; } else if (_r < 54) { _vol = 1; _s = _r - 27; }  \
    int _dx = _s / 9, _dy = (_s / 3) % 3, _dz = _s % 3;                      \
    _vol * VOL_B + ((_dx << 3) + _dy) * LINE_B + _dz * COPY_B; })
  int laneC0 = LANEC(0), laneC1 = LANEC(1), laneC2 = LANEC(2), laneC3 = LANEC(3);
  unsigned int am1 = (q == 1) ? 0u : ~0u;
  unsigned int am2 = (q == 3) ? 0u : ~0u;
  bool isones = (rlo == 6);    // frag3 row 54 = ones
  bool iszero = (rlo > 6);     // frag3 rows 55-63 = zero
  u32x4 one4 = {0x3F803F80u, 0x3F803F80u, 0x3F803F80u, 0x3F803F80u};
  u32x4 zer4 = {0u, 0u, 0u, 0u};

  f32x4 acc0 = {0,0,0,0}, acc1 = {0,0,0,0}, acc2 = {0,0,0,0}, acc3 = {0,0,0,0};
  f32x4 acc4 = {0,0,0,0}, acc5 = {0,0,0,0}, acc6 = {0,0,0,0}, acc7 = {0,0,0,0};
  f32x4 acc8 = {0,0,0,0}, acc9 = {0,0,0,0};

  int npl = (tw * th) >> 1;
  for (int pl = w; pl < npl; pl += 4) {
    int L0 = 2 * pl, L1 = L0 + 1;
    int lx0 = L0 / th, ly0 = L0 - lx0 * th;
    int lx1 = L1 / th, ly1 = L1 - lx1 * th;
    int U0 = ((lx0 << 3) + ly0) * LINE_B;
    int U1 = ((lx1 << 3) + ly1) * LINE_B;
    STEP(U0 + 16 * q, ~0u);
    STEP((q < 2) ? (U0 + 64 + 16 * q) : (U1 + 16 * q - 32), am1);
    STEP(U1 + 32 + 16 * q, am2);
  }
  __syncthreads();

  float* Pf = (float*)smem;
#define FL(T, A) { float* _qp = Pf + w * 2560 + (T) * 256 + lane;            \
    _qp[0] = (A).x; _qp[64] = (A).y; _qp[128] = (A).z; _qp[192] = (A).w; }
  FL(0, acc0) FL(1, acc1) FL(2, acc2) FL(3, acc3) FL(4, acc4)
  FL(5, acc5) FL(6, acc6) FL(7, acc7) FL(8, acc8) FL(9, acc9)
  __syncthreads();
  float* dst = gacc + (size_t)ch * 2560;
  for (int u2 = tid; u2 < 2560; u2 += 256)
    atomicAdd(&dst[u2], Pf[u2] + Pf[u2 + 2560] + Pf[u2 + 5120] + Pf[u2 + 7680]);
}

// ---------------------------------------------------------------------------
// Kernel 3: bordered 54x54 rank-8 blocked elimination (6 phases + 6x6 tail).
// One block per channel, reading the fp32 global Gram (10 KB).
// M = [[pr_cov+aI, B^T],[B, la_cov+aI]]; pivots 27..53 = chol(appro+aI)^2.
// MS even -> 8-double borders are 16-B aligned (ds_read_b128).
// ---------------------------------------------------------------------------
#define MS 56   // row stride (doubles), even for 16-B alignment
__device__ inline double g54(const float* __restrict__ G, int R, int C) {
  int I = R >> 4, J = C >> 4;
  if (I > J) { int tt = R; R = C; C = tt; I = R >> 4; J = C >> 4; }
  int tile = 4 * I - ((I * (I - 1)) >> 1) + (J - I);
  int r = R & 15, c = C & 15;
  return (double)G[tile * 256 + (r & 3) * 64 + ((r >> 2) << 4) + c];
}

__device__ inline int tri_row(int u) {
  int a = (int)((sqrtf(8.0f * (float)u + 1.0f) - 1.0f) * 0.5f);
  while ((a + 1) * (a + 2) / 2 <= u) a++;
  while (a * (a + 1) / 2 > u) a--;
  return a;
}

__global__ __launch_bounds__(256) void stage2_kernel(
    const float* __restrict__ gacc, float* __restrict__ out) {
  __shared__ double M[54 * MS];
  __shared__ double slv[27], spv[27], piv[54], lred[27];
  int ch = blockIdx.x, tid = threadIdx.x;
  const double Minv = 1.0 / (double)NVAL;
  const double alpha = 5e-4;
  const float* G = gacc + (size_t)ch * 2560;

  if (tid < 27) { slv[tid] = g54(G, tid, 54); spv[tid] = g54(G, 27 + tid, 54); }
  __syncthreads();
  // Build lower triangle of bordered matrix: 0..26 = pr dims, 27..53 = la
  for (int u = tid; u < 1485; u += 256) {
    int a = tri_row(u);
    int b = u - a * (a + 1) / 2;               // b <= a
    double v;
    if (a < 27) {                               // pr-pr
      v = g54(G, 27 + a, 27 + b) - spv[a] * spv[b] * Minv + ((a == b) ? alpha : 0.0);
    } else if (b >= 27) {                       // la-la
      int d = a - 27, e = b - 27;
      v = g54(G, d, e) - slv[d] * slv[e] * Minv + ((d == e) ? alpha : 0.0);
    } else {                                    // la row, pr col
      v = g54(G, a - 27, 27 + b) - slv[a - 27] * spv[b] * Minv;
    }
    M[a * MS + b] = v;
  }
  __syncthreads();

  #pragma unroll 1
  for (int phase = 0; phase < 6; phase++) {
    int k0 = phase * 8;
    // Load lower 8x8 pivot block (broadcast reads), factor LDL^T in regs
    double P[8][8];
    #pragma unroll
    for (int k = 0; k < 8; k++)
      #pragma unroll
      for (int j = 0; j <= k; j++)
        P[k][j] = M[(k0 + k) * MS + (k0 + j)];
    double idv[8];
    #pragma unroll
    for (int k = 0; k < 8; k++) {
      idv[k] = 1.0 / P[k][k];
      #pragma unroll
      for (int i = k + 1; i < 8; i++) {
        double l = P[i][k] * idv[k];
        #pragma unroll
        for (int j = k + 1; j <= i; j++)
          P[i][j] -= l * P[j][k];
      }
      #pragma unroll
      for (int i = k + 1; i < 8; i++) P[i][k] *= idv[k];
    }
    if (tid == 0) {
      #pragma unroll
      for (int k = 0; k < 8; k++) piv[k0 + k] = P[k][k];
    }
    int base = k0 + 8, n = 54 - base;
    int ncell = n * (n + 1) / 2;
    for (int u = tid; u < ncell; u += 256) {
      int ii = tri_row(u);
      int jj = u - ii * (ii + 1) / 2;
      int i = base + ii, j = base + jj;
      // 16-B aligned vector loads of the 8-double borders
      const double2* Ai = (const double2*)(M + i * MS + k0);
      const double2* Bj = (const double2*)(M + j * MS + k0);
      double2 a01 = Ai[0], a23 = Ai[1], a45 = Ai[2], a67 = Ai[3];
      double2 b01 = Bj[0], b23 = Bj[1], b45 = Bj[2], b67 = Bj[3];
      double av[8] = {a01.x, a01.y, a23.x, a23.y, a45.x, a45.y, a67.x, a67.y};
      double bv[8] = {b01.x, b01.y, b23.x, b23.y, b45.x, b45.y, b67.x, b67.y};
      #pragma unroll
      for (int k = 1; k < 8; k++) {
        #pragma unroll
        for (int m = 0; m < k; m++) {
          av[k] -= P[k][m] * av[m];
          bv[k] -= P[k][m] * bv[m];
        }
      }
      double acc = 0.0;
      #pragma unroll
      for (int k = 0; k < 8; k++) acc += av[k] * (bv[k] * idv[k]);
      M[i * MS + j] -= acc;
    }
    __syncthreads();
  }

  // Tail: 6x6 trailing block, pivots 48..53
  if (tid == 0) {
    double T[6][6];
    #pragma unroll
    for (int k = 0; k < 6; k++)
      #pragma unroll
      for (int j = 0; j <= k; j++)
        T[k][j] = M[(48 + k) * MS + (48 + j)];
    #pragma unroll
    for (int k = 0; k < 6; k++) {
      double dk = T[k][k];
      piv[48 + k] = dk;
      double id = 1.0 / dk;
      #pragma unroll
      for (int i = k + 1; i < 6; i++) {
        double l = T[i][k] * id;
        #pragma unroll
        for (int j = k + 1; j <= i; j++)
          T[i][j] -= l * T[j][k];
      }
    }
  }
  __syncthreads();

  if (tid < 27) lred[tid] = log(sqrt(piv[27 + tid]) + 1e-8);
  __syncthreads();
  if (tid == 0) {
    double s = 0.0;
    for (int i = 0; i < 27; i++) s += lred[i];
    atomicAdd(out, (float)(s / 54.0));
  }
}

// ---------------------------------------------------------------------------
extern "C" void kernel_launch(void* const* d_in, const int* in_sizes, int n_in,
                              void* d_out, int out_size, void* d_ws, size_t ws_size,
                              hipStream_t stream) {
  const float* logits = (const float*)d_in[0];
  const int* labels = (const int*)d_in[1];
  float* out = (float*)d_out;

  // ws layout: gacc fp32 (80 KB, zeroed by pool) | shifted bf16 (3.6 MB)
  float* gacc = (float*)d_ws;
  u16* shifted = (u16*)((char*)d_ws + 131072);

  pool_kernel<<<864, 256, 0, stream>>>(logits, labels, shifted, gacc, out);
  gram_kernel<<<512, 256, 0, stream>>>(shifted, gacc);
  stage2_kernel<<<NCH, 256, 0, stream>>>(gacc, out);
}